// Round 11
// baseline (412.093 us; speedup 1.0000x reference)
//
#include <hip/hip_runtime.h>
#include <hip/hip_fp16.h>

#define D 128
#define NG 64
#define TILE 4096      // edges per bucket-scatter block
#define BSH 7          // bucket shift: 128 nodes per bucket
#define BNODES 128
#define CAP 4608       // slots per bucket (mean 4096, sigma 64 -> +8 sigma)
#define MASK40 ((1ULL << 40) - 1)
#define FPSCALE 1048576.0f
#define INV_FPSCALE (1.0f / 1048576.0f)
typedef unsigned int uint;
typedef unsigned long long u64;
typedef _Float16 f16x8 __attribute__((ext_vector_type(8)));
typedef float f32x4 __attribute__((ext_vector_type(4)));

// ---------------------------------------------------------------- prep (fused)
__global__ void k_prep(const float* __restrict__ x, __half* __restrict__ xo,
                       const float* __restrict__ Wp, const float* __restrict__ Wn,
                       __half* __restrict__ wpt, __half* __restrict__ wnt,
                       float* sums, float* cnt, int* bktcur,
                       int total4, int nbuk) {
    int i = blockIdx.x * blockDim.x + threadIdx.x;
    if (i < total4) {
        float4 f = ((const float4*)x)[i];
        __half2 h0 = __floats2half2_rn(f.x, f.y);
        __half2 h1 = __floats2half2_rn(f.z, f.w);
        uint2 st;
        st.x = *(uint*)&h0; st.y = *(uint*)&h1;
        ((uint2*)xo)[i] = st;
    }
    if (i < 3 * 128 * 128) {
        int l = i >> 14;
        int r = i & 16383;
        int col = r >> 7, k = r & 127;
        size_t src = ((size_t)l << 14) + ((size_t)k << 7) + col;
        wpt[i] = __float2half_rn(Wp[src]);
        wnt[i] = __float2half_rn(Wn[src]);
    }
    if (i < NG * D) sums[i] = 0.0f;
    if (i < NG) cnt[i] = 0.0f;
    if (i < nbuk) bktcur[i] = i * CAP;
}

// -------------------------------------- pass 1: bucket scatter, LDS-sorted
// record: x = src(16b) | dst_low7(7b)<<16 | bucket(9b)<<23 ; y = w (fp32 bits)
__global__ __launch_bounds__(256) void k_bucket(const int* __restrict__ ei,
                                                const float* __restrict__ ew,
                                                int* bktcur, uint2* rec,
                                                int E, int nbuk) {
    __shared__ int h2[256];
    __shared__ int lofs[512];
    __shared__ int gbase[512];
    __shared__ int lcur[512];
    __shared__ uint2 stg[TILE];
    int t = threadIdx.x;
    lofs[t] = 0; lofs[t + 256] = 0;
    __syncthreads();
    int lo = blockIdx.x * TILE, hi = min(E, lo + TILE);
    int m = hi - lo;
    for (int e = lo + t; e < hi; e += 256)
        atomicAdd(&lofs[ei[(size_t)E + e] >> BSH], 1);
    __syncthreads();
    int c0 = lofs[2 * t], c1 = lofs[2 * t + 1];
    if (c0) gbase[2 * t] = atomicAdd(&bktcur[2 * t], c0);
    if (c1) gbase[2 * t + 1] = atomicAdd(&bktcur[2 * t + 1], c1);
    h2[t] = c0 + c1;
    __syncthreads();
    for (int off = 1; off < 256; off <<= 1) {
        int u = (t >= off) ? h2[t - off] : 0;
        __syncthreads();
        h2[t] += u;
        __syncthreads();
    }
    int excl = h2[t] - (c0 + c1);
    lofs[2 * t] = excl;
    lofs[2 * t + 1] = excl + c0;
    lcur[2 * t] = excl;
    lcur[2 * t + 1] = excl + c0;
    __syncthreads();
    for (int e = lo + t; e < hi; e += 256) {
        int dst = ei[(size_t)E + e];
        int src = ei[e];
        float w = ew[e];
        int b = dst >> BSH;
        int pos = atomicAdd(&lcur[b], 1);
        stg[pos] = make_uint2((uint)src | ((uint)(dst & (BNODES - 1)) << 16) |
                                  ((uint)b << 23),
                              __float_as_uint(w));
    }
    __syncthreads();
    for (int i = t; i < m; i += 256) {
        uint2 r = stg[i];
        int b = (int)(r.x >> 23);
        int gpos = gbase[b] + (i - lofs[b]);
        if (gpos < (b + 1) * CAP)
            rec[gpos] = r;
    }
}

// -------------------------------------- pass 2: per-bucket degrees + row_ptr
__global__ __launch_bounds__(256) void k_deg(const uint2* __restrict__ rec,
                                             const int* __restrict__ bktcur,
                                             float2* dpn, int* row_ptr,
                                             int* cend, int* cpos, int n) {
    __shared__ u64 accp[BNODES], accn[BNODES];
    __shared__ int s[BNODES];
    int b = blockIdx.x, t = threadIdx.x;
    if (t < BNODES) { accp[t] = 0ULL; accn[t] = 0ULL; }
    __syncthreads();
    int lo = b * CAP, hi = bktcur[b];
    for (int i = lo + t; i < hi; i += 256) {
        uint2 r = rec[i];
        int dl = (r.x >> 16) & (BNODES - 1);
        float w = __uint_as_float(r.y);
        u64 pkt = (1ULL << 40) | (u64)(fabsf(w) * FPSCALE + 0.5f);
        atomicAdd((w < 0.0f) ? &accn[dl] : &accp[dl], pkt);
    }
    __syncthreads();
    int cp = 0, cn = 0, cnt_t = 0;
    u64 p = 0, q = 0;
    if (t < BNODES) {
        p = accp[t]; q = accn[t];
        cp = (int)(p >> 40); cn = (int)(q >> 40);
        cnt_t = cp + cn;
        s[t] = cnt_t;
    }
    __syncthreads();
    for (int off = 1; off < BNODES; off <<= 1) {
        int u = 0;
        if (t < BNODES && t >= off) u = s[t - off];
        __syncthreads();
        if (t < BNODES) s[t] += u;
        __syncthreads();
    }
    if (t < BNODES) {
        int node = b * BNODES + t;
        if (node < n) {
            int base = b * CAP + s[t] - cnt_t;
            row_ptr[node] = base;
            cend[node] = base + cnt_t;
            cpos[node] = cp;
            float2 dd;
            dd.x = rsqrtf(1.0f + (float)(p & MASK40) * INV_FPSCALE);
            dd.y = rsqrtf(1.0f + (float)(q & MASK40) * INV_FPSCALE);
            dpn[node] = dd;
        }
    }
}

// -------------------------------------- pass 3: per-bucket CSR pack fill
__global__ __launch_bounds__(256) void k_csr(const uint2* __restrict__ rec,
                                             const int* __restrict__ bktcur,
                                             const int* __restrict__ row_ptr,
                                             const int* __restrict__ cpos,
                                             const float2* __restrict__ dpn,
                                             uint* pack, int n) {
    __shared__ int curp[BNODES], curn[BNODES];
    int b = blockIdx.x, t = threadIdx.x;
    if (t < BNODES) {
        int node = b * BNODES + t;
        if (node < n) {
            int rp = row_ptr[node];
            curp[t] = rp;
            curn[t] = rp + cpos[node];
        } else { curp[t] = 0; curn[t] = 0; }
    }
    __syncthreads();
    int lo = b * CAP, hi = bktcur[b];
    for (int i = lo + t; i < hi; i += 256) {
        uint2 r = rec[i];
        int src = r.x & 0xFFFFu;
        int dl = (r.x >> 16) & (BNODES - 1);
        float w = __uint_as_float(r.y);
        float2 dd = dpn[src];
        float v;
        int slot;
        if (w < 0.0f) { v = dd.y * (-w); slot = atomicAdd(&curn[dl], 1); }
        else          { v = dd.x * w;    slot = atomicAdd(&curp[dl], 1); }
        pack[slot] = (uint)src | ((uint)__half_as_ushort(__float2half_rn(v)) << 16);
    }
}

// -------------------------------------- fused layer: gather + MFMA GEMM + act
// Block = 256 threads = 16 nodes. Wave w gathers nodes node0+4w..+3 (quarter-
// wave split, fp32 accumulate), writes fp16 rows to LDS A-tiles; then each
// wave computes 2 column-tiles x both signs with MFMA (A from LDS, W from L2),
// fused bias + relu-combine epilogue. Verified fragment layouts (m89/m120).
__global__ __launch_bounds__(256) void k_layer(
    const __half* __restrict__ xin, const uint* __restrict__ pack,
    const int* __restrict__ row_ptr, const int* __restrict__ cend,
    const int* __restrict__ cpos, const float2* __restrict__ dpn,
    const __half* __restrict__ wpt, const __half* __restrict__ wnt,
    const float* __restrict__ bp, const float* __restrict__ bn,
    __half* __restrict__ xout, int n) {
    __shared__ uint eb[4][136];
    __shared__ __half atp[16][136];  // stride 136 halves: 2-way banks (free)
    __shared__ __half atn[16][136];
    const int w = threadIdx.x >> 6;
    const int lane = threadIdx.x & 63;
    const int q = lane >> 4;
    const int c = lane & 15;
    const int node0 = blockIdx.x * 16;
    const uint4* __restrict__ x4u = (const uint4*)xin;
    uint* ebw = eb[w];

    // ---- gather phase: 4 nodes per wave
    for (int sub = 0; sub < 4; ++sub) {
        const int node = node0 + w * 4 + sub;
        if (node >= n) break;  // uniform per wave; sync below still reached
        const int beg = row_ptr[node], end = cend[node];
        const int mid = beg + cpos[node];
        const float2 dd = dpn[node];
        uint4 xv = x4u[(size_t)node * 16 + c];
        float xf[8];
        {
            float2 f;
            f = __half22float2(*(__half2*)&xv.x); xf[0] = f.x; xf[1] = f.y;
            f = __half22float2(*(__half2*)&xv.y); xf[2] = f.x; xf[3] = f.y;
            f = __half22float2(*(__half2*)&xv.z); xf[4] = f.x; xf[5] = f.y;
            f = __half22float2(*(__half2*)&xv.w); xf[6] = f.x; xf[7] = f.y;
        }
#pragma unroll
        for (int part = 0; part < 2; ++part) {
            const int lo = part ? mid : beg;
            const int hi = part ? end : mid;
            const float ds = part ? dd.y : dd.x;
            float a0[8], a1[8];
            const float s0 = (q == 0) ? ds : 0.0f;  // self-loop seed
#pragma unroll
            for (int j = 0; j < 8; ++j) { a0[j] = s0 * xf[j]; a1[j] = 0.0f; }
            for (int cb = lo; cb < hi; cb += 128) {
                int m = hi - cb;
                if (m > 128) m = 128;
                const int mp = (m + 7) & ~7;
                for (int i = lane; i < mp; i += 64)
                    ebw[i] = (i < m) ? pack[cb + i] : 0u;  // pad: src=0, v=+0
                for (int i = 0; i < mp; i += 8) {
                    const uint pk0 = ebw[i + q];
                    const uint pk1 = ebw[i + 4 + q];
                    const uint4 y0 = x4u[(size_t)(pk0 & 0xFFFFu) * 16 + c];
                    const uint4 y1 = x4u[(size_t)(pk1 & 0xFFFFu) * 16 + c];
                    const float v0 = __half2float(
                        __ushort_as_half((unsigned short)(pk0 >> 16)));
                    const float v1 = __half2float(
                        __ushort_as_half((unsigned short)(pk1 >> 16)));
                    float2 f;
                    f = __half22float2(*(__half2*)&y0.x);
                    a0[0] = fmaf(v0, f.x, a0[0]); a0[1] = fmaf(v0, f.y, a0[1]);
                    f = __half22float2(*(__half2*)&y0.y);
                    a0[2] = fmaf(v0, f.x, a0[2]); a0[3] = fmaf(v0, f.y, a0[3]);
                    f = __half22float2(*(__half2*)&y0.z);
                    a0[4] = fmaf(v0, f.x, a0[4]); a0[5] = fmaf(v0, f.y, a0[5]);
                    f = __half22float2(*(__half2*)&y0.w);
                    a0[6] = fmaf(v0, f.x, a0[6]); a0[7] = fmaf(v0, f.y, a0[7]);
                    f = __half22float2(*(__half2*)&y1.x);
                    a1[0] = fmaf(v1, f.x, a1[0]); a1[1] = fmaf(v1, f.y, a1[1]);
                    f = __half22float2(*(__half2*)&y1.y);
                    a1[2] = fmaf(v1, f.x, a1[2]); a1[3] = fmaf(v1, f.y, a1[3]);
                    f = __half22float2(*(__half2*)&y1.z);
                    a1[4] = fmaf(v1, f.x, a1[4]); a1[5] = fmaf(v1, f.y, a1[5]);
                    f = __half22float2(*(__half2*)&y1.w);
                    a1[6] = fmaf(v1, f.x, a1[6]); a1[7] = fmaf(v1, f.y, a1[7]);
                }
            }
#pragma unroll
            for (int j = 0; j < 8; ++j) {
                a0[j] += a1[j];
                a0[j] += __shfl_down(a0[j], 32);
                a0[j] += __shfl_down(a0[j], 16);
            }
            if (q == 0) {  // lanes 0..15 hold the full sums -> LDS A-tile
                __half2 h0 = __floats2half2_rn(ds * a0[0], ds * a0[1]);
                __half2 h1 = __floats2half2_rn(ds * a0[2], ds * a0[3]);
                __half2 h2 = __floats2half2_rn(ds * a0[4], ds * a0[5]);
                __half2 h3 = __floats2half2_rn(ds * a0[6], ds * a0[7]);
                uint4 st;
                st.x = *(uint*)&h0; st.y = *(uint*)&h1;
                st.z = *(uint*)&h2; st.w = *(uint*)&h3;
                __half* dstrow = part ? atn[w * 4 + sub] : atp[w * 4 + sub];
                *(uint4*)&dstrow[c * 8] = st;
            }
        }
    }
    __syncthreads();

    // ---- GEMM phase: wave w owns column-tiles 2w, 2w+1 (both signs)
    f16x8 apf[4], anf[4];  // A-frag: A[m=lane&15][k=quad*8+j], shared across ct
#pragma unroll
    for (int kb = 0; kb < 4; ++kb) {
        apf[kb] = *(const f16x8*)&atp[c][kb * 32 + q * 8];
        anf[kb] = *(const f16x8*)&atn[c][kb * 32 + q * 8];
    }
#pragma unroll
    for (int t2 = 0; t2 < 2; ++t2) {
        const int col = (w * 2 + t2) * 16 + c;
        const f16x8* __restrict__ wpr = (const f16x8*)(wpt + (size_t)col * 128);
        const f16x8* __restrict__ wnr = (const f16x8*)(wnt + (size_t)col * 128);
        f32x4 accp = {0.0f, 0.0f, 0.0f, 0.0f};
        f32x4 accn = {0.0f, 0.0f, 0.0f, 0.0f};
#pragma unroll
        for (int kb = 0; kb < 4; ++kb) {
            accp = __builtin_amdgcn_mfma_f32_16x16x32_f16(apf[kb], wpr[kb * 4 + q],
                                                          accp, 0, 0, 0);
            accn = __builtin_amdgcn_mfma_f32_16x16x32_f16(anf[kb], wnr[kb * 4 + q],
                                                          accn, 0, 0, 0);
        }
        const float bpv = bp[col], bnv = bn[col];
#pragma unroll
        for (int reg = 0; reg < 4; ++reg) {
            int row = node0 + q * 4 + reg;  // C/D: col=lane&15, row=quad*4+reg
            if (row < n) {
                float pv = accp[reg] + bpv;
                float nv = accn[reg] + bnv;
                xout[(size_t)row * 128 + col] =
                    __float2half_rn(fmaxf(pv, 0.0f) - fmaxf(nv, 0.0f));
            }
        }
    }
}

// ------------------------------------------------- mean pool (batch sorted)
__global__ __launch_bounds__(128) void k_pool(
    const __half* __restrict__ x, const int* __restrict__ batch,
    float* sums, float* cnt, int n) {
    int f = threadIdx.x;
    int n0 = blockIdx.x * 64;
    int n1 = min(n0 + 64, n);
    float acc = 0.0f;
    int g_prev = batch[n0];
    int local = 0;
    for (int i = n0; i < n1; ++i) {
        int g = batch[i];
        if (g != g_prev) {
            atomicAdd(&sums[g_prev * D + f], acc);
            if (f == 0) atomicAdd(&cnt[g_prev], (float)local);
            acc = 0.0f; local = 0; g_prev = g;
        }
        acc += __half2float(x[(size_t)i * D + f]);
        local++;
    }
    atomicAdd(&sums[g_prev * D + f], acc);
    if (f == 0) atomicAdd(&cnt[g_prev], (float)local);
}

// ------------------------------------------------- layernorm
__global__ __launch_bounds__(128) void k_ln(
    const float* __restrict__ sums, const float* __restrict__ cnt,
    const float* __restrict__ gamma, const float* __restrict__ beta,
    float* __restrict__ out) {
    __shared__ float red[128];
    int g = blockIdx.x, f = threadIdx.x;
    float c = fmaxf(cnt[g], 1.0f);
    float v = sums[g * D + f] / c;
    red[f] = v;
    __syncthreads();
    for (int off = 64; off > 0; off >>= 1) {
        if (f < off) red[f] += red[f + off];
        __syncthreads();
    }
    float mu = red[0] / (float)D;
    __syncthreads();
    float d = v - mu;
    red[f] = d * d;
    __syncthreads();
    for (int off = 64; off > 0; off >>= 1) {
        if (f < off) red[f] += red[f + off];
        __syncthreads();
    }
    float var = red[0] / (float)D;
    out[g * D + f] = d * rsqrtf(var + 1e-5f) * gamma[f] + beta[f];
}

// ================================================================= launch
extern "C" void kernel_launch(void* const* d_in, const int* in_sizes, int n_in,
                              void* d_out, int out_size, void* d_ws,
                              size_t ws_size, hipStream_t stream) {
    const float* x     = (const float*)d_in[0];
    const int*   ei    = (const int*)d_in[1];   // int64 in ref -> int32 here
    const float* ew    = (const float*)d_in[2];
    const int*   bat   = (const int*)d_in[3];   // int64 in ref -> int32 here
    const float* Wp    = (const float*)d_in[4];
    const float* bp    = (const float*)d_in[5];
    const float* Wn    = (const float*)d_in[6];
    const float* bn    = (const float*)d_in[7];
    const float* gamma = (const float*)d_in[8];
    const float* beta  = (const float*)d_in[9];
    const int n = in_sizes[0] / D;       // 50000 (< 65536 required for 4B pack)
    const int E = in_sizes[2];           // 1600000
    const int NBUK = (n + BNODES - 1) >> BSH;     // 391 buckets (<= 512)
    const int NBLK = (E + TILE - 1) / TILE;       // 391 scatter blocks

    float* ws = (float*)d_ws;
    size_t off = 0;
    auto alloc = [&](size_t elems) {  // elems in 4B units, 256B-aligned slots
        float* p = ws + off;
        off += (elems + 63) & ~(size_t)63;
        return p;
    };
    __half* x16  = (__half*)alloc((size_t)n * D / 2);
    __half* xba  = (__half*)alloc((size_t)n * D / 2);
    __half* xbb  = (__half*)alloc((size_t)n * D / 2);
    __half* wpt  = (__half*)alloc(3 * 128 * 128 / 2);
    __half* wnt  = (__half*)alloc(3 * 128 * 128 / 2);
    float2* dpn  = (float2*)alloc((size_t)2 * n);
    float* sums  = alloc(NG * D);
    float* cnt   = alloc(NG);
    int* bktcur  = (int*)alloc(NBUK);
    int* row_ptr = (int*)alloc(n);
    int* cend    = (int*)alloc(n);
    int* cpos    = (int*)alloc(n);
    uint2* rec   = (uint2*)alloc((size_t)NBUK * CAP * 2);
    uint* pack   = (uint*)alloc((size_t)NBUK * CAP);

    k_prep<<<(n * D / 4 + 255) / 256, 256, 0, stream>>>(
        x, x16, Wp, Wn, wpt, wnt, sums, cnt, bktcur, n * D / 4, NBUK);
    k_bucket<<<NBLK, 256, 0, stream>>>(ei, ew, bktcur, rec, E, NBUK);
    k_deg<<<NBUK, 256, 0, stream>>>(rec, bktcur, dpn, row_ptr, cend, cpos, n);
    k_csr<<<NBUK, 256, 0, stream>>>(rec, bktcur, row_ptr, cpos, dpn, pack, n);

    const __half* lin[3]  = {x16, xba, xbb};
    __half*       lout[3] = {xba, xbb, xba};
    for (int l = 0; l < 3; ++l) {
        k_layer<<<(n + 15) / 16, 256, 0, stream>>>(
            lin[l], pack, row_ptr, cend, cpos, dpn,
            wpt + (size_t)l * 128 * 128, wnt + (size_t)l * 128 * 128,
            bp + (size_t)l * D, bn + (size_t)l * D, lout[l], n);
    }
    k_pool<<<(n + 63) / 64, 128, 0, stream>>>(xba, bat, sums, cnt, n);
    k_ln<<<NG, 128, 0, stream>>>(sums, cnt, gamma, beta, (float*)d_out);
}

// Round 12
// 385.771 us; speedup vs baseline: 1.0682x; 1.0682x over previous
//
#include <hip/hip_runtime.h>
#include <hip/hip_fp16.h>

#define D 128
#define NG 64
#define WPB 4          // waves per gather block
#define TILE 4096      // edges per bucket-scatter block
#define BSH 7          // bucket shift: 128 nodes per bucket
#define BNODES 128
#define CAP 4608       // slots per bucket (mean 4096, sigma 64 -> +8 sigma)
#define MASK40 ((1ULL << 40) - 1)
#define FPSCALE 1048576.0f
#define INV_FPSCALE (1.0f / 1048576.0f)
#define GEMM_GRID 512  // persistent gemm blocks (2/CU at 69 KB LDS)
typedef unsigned int uint;
typedef unsigned long long u64;
typedef _Float16 f16x8 __attribute__((ext_vector_type(8)));
typedef float f32x4 __attribute__((ext_vector_type(4)));

// ---------------------------------------------------------------- prep (fused)
__global__ void k_prep(const float* __restrict__ x, __half* __restrict__ xo,
                       const float* __restrict__ Wp, const float* __restrict__ Wn,
                       __half* __restrict__ wpt, __half* __restrict__ wnt,
                       float* sums, float* cnt, int* bktcur,
                       int total4, int nbuk) {
    int i = blockIdx.x * blockDim.x + threadIdx.x;
    if (i < total4) {
        float4 f = ((const float4*)x)[i];
        __half2 h0 = __floats2half2_rn(f.x, f.y);
        __half2 h1 = __floats2half2_rn(f.z, f.w);
        uint2 st;
        st.x = *(uint*)&h0; st.y = *(uint*)&h1;
        ((uint2*)xo)[i] = st;
    }
    if (i < 3 * 128 * 128) {
        int l = i >> 14;
        int r = i & 16383;
        int col = r >> 7, k = r & 127;
        size_t src = ((size_t)l << 14) + ((size_t)k << 7) + col;
        wpt[i] = __float2half_rn(Wp[src]);
        wnt[i] = __float2half_rn(Wn[src]);
    }
    if (i < NG * D) sums[i] = 0.0f;
    if (i < NG) cnt[i] = 0.0f;
    if (i < nbuk) bktcur[i] = i * CAP;
}

// -------------------------------------- pass 1: bucket scatter, LDS-sorted
// record: x = src(16b) | dst_low7(7b)<<16 | bucket(9b)<<23 ; y = w (fp32 bits)
__global__ __launch_bounds__(256) void k_bucket(const int* __restrict__ ei,
                                                const float* __restrict__ ew,
                                                int* bktcur, uint2* rec,
                                                int E, int nbuk) {
    __shared__ int h2[256];
    __shared__ int lofs[512];
    __shared__ int gbase[512];
    __shared__ int lcur[512];
    __shared__ uint2 stg[TILE];
    int t = threadIdx.x;
    lofs[t] = 0; lofs[t + 256] = 0;
    __syncthreads();
    int lo = blockIdx.x * TILE, hi = min(E, lo + TILE);
    int m = hi - lo;
    for (int e = lo + t; e < hi; e += 256)
        atomicAdd(&lofs[ei[(size_t)E + e] >> BSH], 1);
    __syncthreads();
    int c0 = lofs[2 * t], c1 = lofs[2 * t + 1];
    if (c0) gbase[2 * t] = atomicAdd(&bktcur[2 * t], c0);
    if (c1) gbase[2 * t + 1] = atomicAdd(&bktcur[2 * t + 1], c1);
    h2[t] = c0 + c1;
    __syncthreads();
    for (int off = 1; off < 256; off <<= 1) {
        int u = (t >= off) ? h2[t - off] : 0;
        __syncthreads();
        h2[t] += u;
        __syncthreads();
    }
    int excl = h2[t] - (c0 + c1);
    lofs[2 * t] = excl;
    lofs[2 * t + 1] = excl + c0;
    lcur[2 * t] = excl;
    lcur[2 * t + 1] = excl + c0;
    __syncthreads();
    for (int e = lo + t; e < hi; e += 256) {
        int dst = ei[(size_t)E + e];
        int src = ei[e];
        float w = ew[e];
        int b = dst >> BSH;
        int pos = atomicAdd(&lcur[b], 1);
        stg[pos] = make_uint2((uint)src | ((uint)(dst & (BNODES - 1)) << 16) |
                                  ((uint)b << 23),
                              __float_as_uint(w));
    }
    __syncthreads();
    for (int i = t; i < m; i += 256) {
        uint2 r = stg[i];
        int b = (int)(r.x >> 23);
        int gpos = gbase[b] + (i - lofs[b]);
        if (gpos < (b + 1) * CAP)
            rec[gpos] = r;
    }
}

// -------------------------------------- pass 2: per-bucket degrees + row_ptr
__global__ __launch_bounds__(256) void k_deg(const uint2* __restrict__ rec,
                                             const int* __restrict__ bktcur,
                                             float2* dpn, int* row_ptr,
                                             int* cend, int* cpos, int n) {
    __shared__ u64 accp[BNODES], accn[BNODES];
    __shared__ int s[BNODES];
    int b = blockIdx.x, t = threadIdx.x;
    if (t < BNODES) { accp[t] = 0ULL; accn[t] = 0ULL; }
    __syncthreads();
    int lo = b * CAP, hi = bktcur[b];
    for (int i = lo + t; i < hi; i += 256) {
        uint2 r = rec[i];
        int dl = (r.x >> 16) & (BNODES - 1);
        float w = __uint_as_float(r.y);
        u64 pkt = (1ULL << 40) | (u64)(fabsf(w) * FPSCALE + 0.5f);
        atomicAdd((w < 0.0f) ? &accn[dl] : &accp[dl], pkt);
    }
    __syncthreads();
    int cp = 0, cn = 0, cnt_t = 0;
    u64 p = 0, q = 0;
    if (t < BNODES) {
        p = accp[t]; q = accn[t];
        cp = (int)(p >> 40); cn = (int)(q >> 40);
        cnt_t = cp + cn;
        s[t] = cnt_t;
    }
    __syncthreads();
    for (int off = 1; off < BNODES; off <<= 1) {
        int u = 0;
        if (t < BNODES && t >= off) u = s[t - off];
        __syncthreads();
        if (t < BNODES) s[t] += u;
        __syncthreads();
    }
    if (t < BNODES) {
        int node = b * BNODES + t;
        if (node < n) {
            int base = b * CAP + s[t] - cnt_t;
            row_ptr[node] = base;
            cend[node] = base + cnt_t;
            cpos[node] = cp;
            float2 dd;
            dd.x = rsqrtf(1.0f + (float)(p & MASK40) * INV_FPSCALE);
            dd.y = rsqrtf(1.0f + (float)(q & MASK40) * INV_FPSCALE);
            dpn[node] = dd;
        }
    }
}

// -------------------------------------- pass 3: per-bucket CSR pack fill
__global__ __launch_bounds__(256) void k_csr(const uint2* __restrict__ rec,
                                             const int* __restrict__ bktcur,
                                             const int* __restrict__ row_ptr,
                                             const int* __restrict__ cpos,
                                             const float2* __restrict__ dpn,
                                             uint* pack, int n) {
    __shared__ int curp[BNODES], curn[BNODES];
    int b = blockIdx.x, t = threadIdx.x;
    if (t < BNODES) {
        int node = b * BNODES + t;
        if (node < n) {
            int rp = row_ptr[node];
            curp[t] = rp;
            curn[t] = rp + cpos[node];
        } else { curp[t] = 0; curn[t] = 0; }
    }
    __syncthreads();
    int lo = b * CAP, hi = bktcur[b];
    for (int i = lo + t; i < hi; i += 256) {
        uint2 r = rec[i];
        int src = r.x & 0xFFFFu;
        int dl = (r.x >> 16) & (BNODES - 1);
        float w = __uint_as_float(r.y);
        float2 dd = dpn[src];
        float v;
        int slot;
        if (w < 0.0f) { v = dd.y * (-w); slot = atomicAdd(&curn[dl], 1); }
        else          { v = dd.x * w;    slot = atomicAdd(&curp[dl], 1); }
        pack[slot] = (uint)src | ((uint)__half_as_ushort(__float2half_rn(v)) << 16);
    }
}

// -------------------------------------- gather: fp16 rows, quarter-wave split
// wave = one node, NO barriers -> independent wave retirement (round-11 lesson:
// barrier-coupled fusion with GEMM regressed; keep this standalone).
__global__ __launch_bounds__(64 * WPB) void k_gather(
    const __half* __restrict__ x16, const uint* __restrict__ pack,
    const int* __restrict__ row_ptr, const int* __restrict__ cend,
    const int* __restrict__ cpos, const float2* __restrict__ dpn,
    __half* __restrict__ tp, __half* __restrict__ tn, int n) {
    __shared__ uint eb[WPB][136];
    const int w = threadIdx.x >> 6;
    const int lane = threadIdx.x & 63;
    const int q = lane >> 4;
    const int c = lane & 15;
    const int node = blockIdx.x * WPB + w;
    if (node >= n) return;
    const int beg = row_ptr[node], end = cend[node];
    const int mid = beg + cpos[node];
    const float2 dd = dpn[node];
    const uint4* __restrict__ x4u = (const uint4*)x16;
    uint* ebw = eb[w];

    uint4 xv = x4u[(size_t)node * 16 + c];
    float xf[8];
    {
        float2 f;
        f = __half22float2(*(__half2*)&xv.x); xf[0] = f.x; xf[1] = f.y;
        f = __half22float2(*(__half2*)&xv.y); xf[2] = f.x; xf[3] = f.y;
        f = __half22float2(*(__half2*)&xv.z); xf[4] = f.x; xf[5] = f.y;
        f = __half22float2(*(__half2*)&xv.w); xf[6] = f.x; xf[7] = f.y;
    }

#pragma unroll
    for (int part = 0; part < 2; ++part) {
        const int lo = part ? mid : beg;
        const int hi = part ? end : mid;
        const float ds = part ? dd.y : dd.x;
        float a0[8], a1[8];
        const float s0 = (q == 0) ? ds : 0.0f;  // self-loop seed, quarter 0 only
#pragma unroll
        for (int j = 0; j < 8; ++j) { a0[j] = s0 * xf[j]; a1[j] = 0.0f; }
        for (int cb = lo; cb < hi; cb += 128) {
            int m = hi - cb;
            if (m > 128) m = 128;
            const int mp = (m + 7) & ~7;
            for (int i = lane; i < mp; i += 64)
                ebw[i] = (i < m) ? pack[cb + i] : 0u;  // pad: src=0, v=+0.0
            for (int i = 0; i < mp; i += 8) {
                const uint pk0 = ebw[i + q];
                const uint pk1 = ebw[i + 4 + q];
                const uint4 y0 = x4u[(size_t)(pk0 & 0xFFFFu) * 16 + c];
                const uint4 y1 = x4u[(size_t)(pk1 & 0xFFFFu) * 16 + c];
                const float v0 =
                    __half2float(__ushort_as_half((unsigned short)(pk0 >> 16)));
                const float v1 =
                    __half2float(__ushort_as_half((unsigned short)(pk1 >> 16)));
                float2 f;
                f = __half22float2(*(__half2*)&y0.x);
                a0[0] = fmaf(v0, f.x, a0[0]); a0[1] = fmaf(v0, f.y, a0[1]);
                f = __half22float2(*(__half2*)&y0.y);
                a0[2] = fmaf(v0, f.x, a0[2]); a0[3] = fmaf(v0, f.y, a0[3]);
                f = __half22float2(*(__half2*)&y0.z);
                a0[4] = fmaf(v0, f.x, a0[4]); a0[5] = fmaf(v0, f.y, a0[5]);
                f = __half22float2(*(__half2*)&y0.w);
                a0[6] = fmaf(v0, f.x, a0[6]); a0[7] = fmaf(v0, f.y, a0[7]);
                f = __half22float2(*(__half2*)&y1.x);
                a1[0] = fmaf(v1, f.x, a1[0]); a1[1] = fmaf(v1, f.y, a1[1]);
                f = __half22float2(*(__half2*)&y1.y);
                a1[2] = fmaf(v1, f.x, a1[2]); a1[3] = fmaf(v1, f.y, a1[3]);
                f = __half22float2(*(__half2*)&y1.z);
                a1[4] = fmaf(v1, f.x, a1[4]); a1[5] = fmaf(v1, f.y, a1[5]);
                f = __half22float2(*(__half2*)&y1.w);
                a1[6] = fmaf(v1, f.x, a1[6]); a1[7] = fmaf(v1, f.y, a1[7]);
            }
        }
#pragma unroll
        for (int j = 0; j < 8; ++j) {
            a0[j] += a1[j];
            a0[j] += __shfl_down(a0[j], 32);
            a0[j] += __shfl_down(a0[j], 16);
        }
        if (q == 0) {  // lanes 0..15 hold the full sums
            __half2 h0 = __floats2half2_rn(ds * a0[0], ds * a0[1]);
            __half2 h1 = __floats2half2_rn(ds * a0[2], ds * a0[3]);
            __half2 h2 = __floats2half2_rn(ds * a0[4], ds * a0[5]);
            __half2 h3 = __floats2half2_rn(ds * a0[6], ds * a0[7]);
            uint4 st;
            st.x = *(uint*)&h0; st.y = *(uint*)&h1;
            st.z = *(uint*)&h2; st.w = *(uint*)&h3;
            ((uint4*)(part ? tn : tp))[(size_t)node * 16 + c] = st;
        }
    }
}

// ------------------------------------------------- MFMA dual GEMM v3: persistent
// 512 blocks (2/CU) stage W into LDS ONCE, then grid-stride over 64-row tiles.
// Amortizes v2's per-block staging latency. Verified fragment layouts (m89/m120).
__global__ __launch_bounds__(256) void k_gemm(
    const __half* __restrict__ tp, const __half* __restrict__ tn,
    const __half* __restrict__ wpt, const __half* __restrict__ wnt,
    const float* __restrict__ bp, const float* __restrict__ bn,
    __half* __restrict__ xout, int nrows, int ntiles) {
    __shared__ __half wlds[2][128][136];
    const int tid = threadIdx.x;
    {
        const uint4* wp4 = (const uint4*)wpt;
        const uint4* wn4 = (const uint4*)wnt;
#pragma unroll
        for (int j = 0; j < 8; ++j) {
            int idx = tid + j * 256;   // 2048 uint4 = 16384 halves per sign
            int col = idx >> 4;
            int k8 = idx & 15;
            *(uint4*)&wlds[0][col][k8 * 8] = wp4[idx];
            *(uint4*)&wlds[1][col][k8 * 8] = wn4[idx];
        }
    }
    const int wave = tid >> 6;
    const int lane = tid & 63;
    const int cl = lane & 15;
    const int quad = lane >> 4;
    __syncthreads();
    for (int rt = blockIdx.x; rt < ntiles; rt += GEMM_GRID) {
        const int row_blk = rt * 64 + wave * 16;
        if (row_blk >= nrows) continue;
        int arow = row_blk + cl;
        if (arow >= nrows) arow = nrows - 1;  // clamp loads; stores guarded
        const f16x8* __restrict__ tpr = (const f16x8*)(tp + (size_t)arow * 128);
        const f16x8* __restrict__ tnr = (const f16x8*)(tn + (size_t)arow * 128);
        f16x8 ap[4], an[4];
#pragma unroll
        for (int kb = 0; kb < 4; ++kb) {
            ap[kb] = tpr[kb * 4 + quad];
            an[kb] = tnr[kb * 4 + quad];
        }
#pragma unroll
        for (int ct = 0; ct < 8; ++ct) {
            const int col = ct * 16 + cl;
            f32x4 accp = {0.0f, 0.0f, 0.0f, 0.0f};
            f32x4 accn = {0.0f, 0.0f, 0.0f, 0.0f};
#pragma unroll
            for (int kb = 0; kb < 4; ++kb) {
                f16x8 wfp = *(const f16x8*)&wlds[0][col][kb * 32 + quad * 8];
                f16x8 wfn = *(const f16x8*)&wlds[1][col][kb * 32 + quad * 8];
                accp = __builtin_amdgcn_mfma_f32_16x16x32_f16(ap[kb], wfp, accp,
                                                              0, 0, 0);
                accn = __builtin_amdgcn_mfma_f32_16x16x32_f16(an[kb], wfn, accn,
                                                              0, 0, 0);
            }
            const float bpv = bp[col], bnv = bn[col];
#pragma unroll
            for (int reg = 0; reg < 4; ++reg) {
                int row = row_blk + quad * 4 + reg;
                if (row < nrows) {
                    float pv = accp[reg] + bpv;
                    float nv = accn[reg] + bnv;
                    xout[(size_t)row * 128 + col] =
                        __float2half_rn(fmaxf(pv, 0.0f) - fmaxf(nv, 0.0f));
                }
            }
        }
    }
}

// ------------------------------------------------- mean pool (batch sorted)
__global__ __launch_bounds__(128) void k_pool(
    const __half* __restrict__ x, const int* __restrict__ batch,
    float* sums, float* cnt, int n) {
    int f = threadIdx.x;
    int n0 = blockIdx.x * 64;
    int n1 = min(n0 + 64, n);
    float acc = 0.0f;
    int g_prev = batch[n0];
    int local = 0;
    for (int i = n0; i < n1; ++i) {
        int g = batch[i];
        if (g != g_prev) {
            atomicAdd(&sums[g_prev * D + f], acc);
            if (f == 0) atomicAdd(&cnt[g_prev], (float)local);
            acc = 0.0f; local = 0; g_prev = g;
        }
        acc += __half2float(x[(size_t)i * D + f]);
        local++;
    }
    atomicAdd(&sums[g_prev * D + f], acc);
    if (f == 0) atomicAdd(&cnt[g_prev], (float)local);
}

// ------------------------------------------------- layernorm
__global__ __launch_bounds__(128) void k_ln(
    const float* __restrict__ sums, const float* __restrict__ cnt,
    const float* __restrict__ gamma, const float* __restrict__ beta,
    float* __restrict__ out) {
    __shared__ float red[128];
    int g = blockIdx.x, f = threadIdx.x;
    float c = fmaxf(cnt[g], 1.0f);
    float v = sums[g * D + f] / c;
    red[f] = v;
    __syncthreads();
    for (int off = 64; off > 0; off >>= 1) {
        if (f < off) red[f] += red[f + off];
        __syncthreads();
    }
    float mu = red[0] / (float)D;
    __syncthreads();
    float d = v - mu;
    red[f] = d * d;
    __syncthreads();
    for (int off = 64; off > 0; off >>= 1) {
        if (f < off) red[f] += red[f + off];
        __syncthreads();
    }
    float var = red[0] / (float)D;
    out[g * D + f] = d * rsqrtf(var + 1e-5f) * gamma[f] + beta[f];
}

// ================================================================= launch
extern "C" void kernel_launch(void* const* d_in, const int* in_sizes, int n_in,
                              void* d_out, int out_size, void* d_ws,
                              size_t ws_size, hipStream_t stream) {
    const float* x     = (const float*)d_in[0];
    const int*   ei    = (const int*)d_in[1];   // int64 in ref -> int32 here
    const float* ew    = (const float*)d_in[2];
    const int*   bat   = (const int*)d_in[3];   // int64 in ref -> int32 here
    const float* Wp    = (const float*)d_in[4];
    const float* bp    = (const float*)d_in[5];
    const float* Wn    = (const float*)d_in[6];
    const float* bn    = (const float*)d_in[7];
    const float* gamma = (const float*)d_in[8];
    const float* beta  = (const float*)d_in[9];
    const int n = in_sizes[0] / D;       // 50000 (< 65536 required for 4B pack)
    const int E = in_sizes[2];           // 1600000
    const int NBUK = (n + BNODES - 1) >> BSH;     // 391 buckets (<= 512)
    const int NBLK = (E + TILE - 1) / TILE;       // 391 scatter blocks
    const int NT = (n + 63) / 64;                 // 782 gemm row-tiles

    float* ws = (float*)d_ws;
    size_t off = 0;
    auto alloc = [&](size_t elems) {  // elems in 4B units, 256B-aligned slots
        float* p = ws + off;
        off += (elems + 63) & ~(size_t)63;
        return p;
    };
    __half* x16  = (__half*)alloc((size_t)n * D / 2);
    __half* tpb  = (__half*)alloc((size_t)n * D / 2);
    __half* tnb  = (__half*)alloc((size_t)n * D / 2);
    __half* xb   = (__half*)alloc((size_t)n * D / 2);
    __half* wpt  = (__half*)alloc(3 * 128 * 128 / 2);
    __half* wnt  = (__half*)alloc(3 * 128 * 128 / 2);
    float2* dpn  = (float2*)alloc((size_t)2 * n);
    float* sums  = alloc(NG * D);
    float* cnt   = alloc(NG);
    int* bktcur  = (int*)alloc(NBUK);
    int* row_ptr = (int*)alloc(n);
    int* cend    = (int*)alloc(n);
    int* cpos    = (int*)alloc(n);
    uint2* rec   = (uint2*)alloc((size_t)NBUK * CAP * 2);
    uint* pack   = (uint*)alloc((size_t)NBUK * CAP);

    k_prep<<<(n * D / 4 + 255) / 256, 256, 0, stream>>>(
        x, x16, Wp, Wn, wpt, wnt, sums, cnt, bktcur, n * D / 4, NBUK);
    k_bucket<<<NBLK, 256, 0, stream>>>(ei, ew, bktcur, rec, E, NBUK);
    k_deg<<<NBUK, 256, 0, stream>>>(rec, bktcur, dpn, row_ptr, cend, cpos, n);
    k_csr<<<NBUK, 256, 0, stream>>>(rec, bktcur, row_ptr, cpos, dpn, pack, n);

    const __half* xcur = x16;
    for (int l = 0; l < 3; ++l) {
        k_gather<<<(n + WPB - 1) / WPB, 64 * WPB, 0, stream>>>(
            xcur, pack, row_ptr, cend, cpos, dpn, tpb, tnb, n);
        k_gemm<<<GEMM_GRID, 256, 0, stream>>>(
            tpb, tnb, wpt + (size_t)l * 128 * 128, wnt + (size_t)l * 128 * 128,
            bp + (size_t)l * D, bn + (size_t)l * D, xb, n, NT);
        xcur = xb;
    }
    k_pool<<<(n + 63) / 64, 128, 0, stream>>>(xb, bat, sums, cnt, n);
    k_ln<<<NG, 128, 0, stream>>>(sums, cnt, gamma, beta, (float*)d_out);
}